// Round 3
// baseline (131.003 us; speedup 1.0000x reference)
//
#include <hip/hip_runtime.h>

#define LOG2E 1.4426950408889634f

// Problem constants
constexpr int Bb = 4, LQ = 512, LK = 512, QS = 512, H = 256, DV = 512;
constexpr int M = 2048;   // B*LQ

// Workspace byte offsets
constexpr size_t OFF_EQT = 0;             // [256][2048] f32 (2 MiB) exp2-domain q proj (pre-scaled 2^-13)
constexpr size_t OFF_EKT = 2u << 20;      // [256][2048] f32 (2 MiB)
constexpr size_t OFF_PQ  = 4u << 20;      // [4][512][512] bf16 (2 MiB) P numerators
constexpr size_t OFF_ROW = 6u << 20;      // [8][2048] f32 rowsum partials
constexpr size_t OFF_VT  = 8u << 20;      // [4][512][512] bf16 V^T ([b][n][k]) (2 MiB)
constexpr size_t OFF_ABF = 10u << 20;     // [2][2048][512] bf16 q/k inputs (4 MiB)
constexpr size_t OFF_WBF = 14u << 20;     // [2][256][512] bf16 wq/wk (512 KiB)

constexpr int QN = 2048 * 512;            // elems in one A matrix
constexpr int WN = 256 * 512;             // elems in one W matrix

using bf16x8 = __attribute__((ext_vector_type(8))) short;
using f32x4v = __attribute__((ext_vector_type(4))) float;

__device__ inline unsigned short f2bf(float x) {
    unsigned int u = __float_as_uint(x);
    u += 0x7FFFu + ((u >> 16) & 1u);      // round-to-nearest-even
    return (unsigned short)(u >> 16);
}
// HW packed f32->bf16 (RNE, matches f2bf bit-for-bit on finite inputs).
__device__ inline unsigned int pk2(float lo, float hi) {
    unsigned int r;
    asm("v_cvt_pk_bf16_f32 %0, %1, %2" : "=v"(r) : "v"(lo), "v"(hi));
    return r;
}

// ---------------------------------------------------------------------------
// Kernel 0 (R17): preconv — all f32->bf16 conversions in one pass.
//   z=0: flat RNE convert of {query,key}->ABF[2][2048][512], {wq,wk}->WBF.
//   z=1: V -> bf16 V^T [b][n][k] (the old vconv, folded in).
// Removes the per-block cvt_pk staging chains from both GEMMs and one
// kernel launch.  Values bit-identical to the old in-kernel conversion.
// ---------------------------------------------------------------------------
__global__ __launch_bounds__(256) void preconv(
    const float* __restrict__ query, const float* __restrict__ key,
    const float* __restrict__ wq, const float* __restrict__ wk,
    const float* __restrict__ V, char* __restrict__ ws)
{
    const int tid = threadIdx.x;
    if (blockIdx.z == 0) {
        // 576 blocks x 256 thr x 16 elems = 2359296 = 2*QN + 2*WN exactly.
        int base = (blockIdx.x * 256 + tid) * 16;
        const float* src;
        unsigned short* dst;
        if (base < QN) {
            src = query + base;
            dst = (unsigned short*)(ws + OFF_ABF) + base;
        } else if (base < 2 * QN) {
            src = key + (base - QN);
            dst = (unsigned short*)(ws + OFF_ABF) + base;
        } else if (base < 2 * QN + WN) {
            src = wq + (base - 2 * QN);
            dst = (unsigned short*)(ws + OFF_WBF) + (base - 2 * QN);
        } else {
            src = wk + (base - 2 * QN - WN);
            dst = (unsigned short*)(ws + OFF_WBF) + (base - 2 * QN);  // WN offset kept: base-2QN in [WN,2WN)
        }
        float4 a = *(const float4*)(src);
        float4 b = *(const float4*)(src + 4);
        float4 c = *(const float4*)(src + 8);
        float4 d = *(const float4*)(src + 12);
        uint4 o0 = { pk2(a.x, a.y), pk2(a.z, a.w), pk2(b.x, b.y), pk2(b.z, b.w) };
        uint4 o1 = { pk2(c.x, c.y), pk2(c.z, c.w), pk2(d.x, d.y), pk2(d.z, d.w) };
        *(uint4*)(dst)     = o0;
        *(uint4*)(dst + 8) = o1;
    } else {
        if (blockIdx.x >= 256) return;
        unsigned short* VT = (unsigned short*)(ws + OFF_VT);
        __shared__ unsigned short T[64][72];
        const int id = blockIdx.x;
        const int b = id >> 6, k0 = (id & 7) * 64, n0 = ((id >> 3) & 7) * 64;
        const float* Vb = V + (size_t)b * 512 * 512;
        const int r = tid >> 4, c = (tid & 15) * 4;
#pragma unroll
        for (int it = 0; it < 4; ++it) {
            int kr = r + it * 16;
            float4 v = *(const float4*)(Vb + (size_t)(k0 + kr) * 512 + n0 + c);
            T[c + 0][kr] = f2bf(v.x);
            T[c + 1][kr] = f2bf(v.y);
            T[c + 2][kr] = f2bf(v.z);
            T[c + 3][kr] = f2bf(v.w);
        }
        __syncthreads();
        const int rowO = tid >> 3, colO = (tid & 7) * 8;
#pragma unroll
        for (int it = 0; it < 2; ++it) {
            int n = rowO + it * 32;
            uint4 o = *(const uint4*)&T[n][colO];
            *(uint4*)(VT + ((size_t)b * 512 + n0 + n) * 512 + k0 + colO) = o;
        }
    }
}

// ---------------------------------------------------------------------------
// Kernel A (R17): proj via direct-from-global bf16 MFMA fragments.
// No LDS staging, no K-loop barriers: the 16x16x32 A/B fragment is 8
// contiguous bf16 at row ml, k=quad*8 — a single dwordx4 from the
// row-major bf16 arrays.  W is L1/L2-resident (256 KB), A L2/L3-resident.
// 512 thr: wave (wid&3)=m-subtile, (wid>>2)=n-half.  k-order identical to
// the old LDS version -> bit-identical EqT/EkT.
//   EqT[n][m] = exp2( clamp( scale*(A[m]·W[n] + bias[n]), ±13 ) - 13 )  (z=0)
//   EkT[n][m] = exp2( clamp( ..., ±13 ) )                                (z=1)
// ---------------------------------------------------------------------------
__global__ __launch_bounds__(512, 2) void proj_mfma(
    const float* __restrict__ bq, const float* __restrict__ bk,
    char* __restrict__ ws, float scale)
{
    const int z = blockIdx.z;
    const unsigned short* Abf = (const unsigned short*)(ws + OFF_ABF) + (size_t)z * QN;
    const unsigned short* Wbf = (const unsigned short*)(ws + OFF_WBF) + (size_t)z * WN;
    const float* bias = z ? bk : bq;
    float* out = (float*)(ws + (z ? OFF_EKT : OFF_EQT));   // [256][2048]
    const float off = z ? 0.0f : 13.0f;

    __shared__ float Ot[64][68];

    const int mb = blockIdx.x * 64, nb = blockIdx.y * 64;
    const int tid = threadIdx.x;
    const int wid = tid >> 6, lane = tid & 63;
    const int ml = lane & 15, quad = lane >> 4;
    const int ms = wid & 3, nh = wid >> 2;

    const unsigned short* Ap  = Abf + (size_t)(mb + ms * 16 + ml) * 512 + quad * 8;
    const unsigned short* Wp0 = Wbf + (size_t)(nb + (nh * 2 + 0) * 16 + ml) * 512 + quad * 8;
    const unsigned short* Wp1 = Wbf + (size_t)(nb + (nh * 2 + 1) * 16 + ml) * 512 + quad * 8;

    f32x4v acc0 = {0, 0, 0, 0}, acc1 = {0, 0, 0, 0};
#pragma unroll
    for (int kk = 0; kk < 16; ++kk) {
        bf16x8 af = *(const bf16x8*)(Ap  + kk * 32);
        bf16x8 b0 = *(const bf16x8*)(Wp0 + kk * 32);
        bf16x8 b1 = *(const bf16x8*)(Wp1 + kk * 32);
        acc0 = __builtin_amdgcn_mfma_f32_16x16x32_bf16(af, b0, acc0, 0, 0, 0);
        acc1 = __builtin_amdgcn_mfma_f32_16x16x32_bf16(af, b1, acc1, 0, 0, 0);
    }

    __syncthreads();
#pragma unroll
    for (int r = 0; r < 4; ++r) {
        Ot[(nh * 2 + 0) * 16 + ml][ms * 16 + quad * 4 + r] = acc0[r];
        Ot[(nh * 2 + 1) * 16 + ml][ms * 16 + quad * 4 + r] = acc1[r];
    }
    __syncthreads();
    {
        int r0 = tid >> 3;            // n-local 0..63
        int c0 = (tid & 7) * 8;       // m-local base
        float bs = bias[nb + r0];
#pragma unroll
        for (int g = 0; g < 2; ++g) {
            float4 v = *(const float4*)&Ot[r0][c0 + g * 4];
            float4 o;
            o.x = __builtin_amdgcn_exp2f(fminf(fmaxf(scale * (v.x + bs), -13.f), 13.f) - off);
            o.y = __builtin_amdgcn_exp2f(fminf(fmaxf(scale * (v.y + bs), -13.f), 13.f) - off);
            o.z = __builtin_amdgcn_exp2f(fminf(fmaxf(scale * (v.z + bs), -13.f), 13.f) - off);
            o.w = __builtin_amdgcn_exp2f(fminf(fmaxf(scale * (v.w + bs), -13.f), 13.f) - off);
            *(float4*)(out + (size_t)(nb + r0) * 2048 + mb + c0 + g * 4) = o;
        }
    }
}

// ---------------------------------------------------------------------------
// Kernel B: scores -> P = exp2(-acc) bf16 [b][q][k] + per-ktile row partials.
//   acc(q,k) = sum_h Wv2[h]/(1 + Eq[h][q]*Ek[h][k])   (8-way rcp pairing,
//   s=2^-13 pre-folded into Eq and Wv2 -> exact ratio, no overflow)
// (unchanged from R16)
// ---------------------------------------------------------------------------
__global__ __launch_bounds__(512, 4) void score_kernel(
    const float* __restrict__ wvp, char* __restrict__ ws)
{
    const float* EqT = (const float*)(ws + OFF_EQT);   // [256][2048], pre-scaled 2^-13
    const float* EkT = (const float*)(ws + OFF_EKT);
    unsigned short* Pq = (unsigned short*)(ws + OFF_PQ);  // [4][512][512] bf16
    float* rowpart = (float*)(ws + OFF_ROW);              // [8][2048]

    __shared__ float Qs[64][32];
    __shared__ float Ks[64][64];
    __shared__ float Wv2[H];
    __shared__ float redS[8][32];

    const int b  = blockIdx.z;
    const int qb = blockIdx.x * 32;
    const int kt = blockIdx.y;
    const int kb = kt * 64;
    const int tid = threadIdx.x;
    const int tx = tid & 15;       // q frag: tx*2 + i
    const int ty = tid >> 4;       // k frag: ty*2 + j   (0..31)
    const int w  = tid >> 6;       // 0..7
    const int lane = tid & 63;

    constexpr float S = 0.0001220703125f;   // 2^-13
    if (tid < H) Wv2[tid] = wvp[tid] * (2.0f * LOG2E) * S;   // fold one s into w

    const int mq = b * LQ + qb;
    const int mk = b * LK + kb;

    float acc[2][2] = {};

    for (int h0 = 0; h0 < H; h0 += 64) {
        __syncthreads();   // also covers the Wv2 write on the first pass
        {
            int hq = tid >> 3, cq = (tid & 7) * 4;
            *(float4*)&Qs[hq][cq] = *(const float4*)(EqT + (size_t)(h0 + hq) * M + mq + cq);
            int hk = tid >> 4, ck = (tid & 15) * 4;
            *(float4*)&Ks[hk][ck]      = *(const float4*)(EkT + (size_t)(h0 + hk) * M + mk + ck);
            *(float4*)&Ks[hk + 32][ck] = *(const float4*)(EkT + (size_t)(h0 + hk + 32) * M + mk + ck);
        }
        __syncthreads();
#pragma unroll 2
        for (int hh = 0; hh < 64; hh += 8) {
            float2 qv[8], kv[8];
#pragma unroll
            for (int u = 0; u < 8; ++u) qv[u] = *(const float2*)&Qs[hh + u][tx * 2];
#pragma unroll
            for (int u = 0; u < 8; ++u) kv[u] = *(const float2*)&Ks[hh + u][ty * 2];
            const float4 wA = *(const float4*)&Wv2[h0 + hh];
            const float4 wB = *(const float4*)&Wv2[h0 + hh + 4];
#pragma unroll
            for (int i = 0; i < 2; ++i)
#pragma unroll
                for (int j = 0; j < 2; ++j) {
                    float t[8];
#pragma unroll
                    for (int u = 0; u < 8; ++u)
                        t[u] = fmaf(i ? qv[u].y : qv[u].x, j ? kv[u].y : kv[u].x, S);
                    float t12 = t[0] * t[1], t34 = t[2] * t[3];
                    float n12 = fmaf(wA.x, t[1], wA.y * t[0]);
                    float n34 = fmaf(wA.z, t[3], wA.w * t[2]);
                    float numA = fmaf(n12, t34, n34 * t12);
                    float denA = t12 * t34;
                    float t56 = t[4] * t[5], t78 = t[6] * t[7];
                    float m12 = fmaf(wB.x, t[5], wB.y * t[4]);
                    float m34 = fmaf(wB.z, t[7], wB.w * t[6]);
                    float numB = fmaf(m12, t78, m34 * t56);
                    float denB = t56 * t78;
                    float NUMv = fmaf(numA, denB, numB * denA);
                    float DENv = denA * denB;
                    acc[i][j] = fmaf(NUMv, __builtin_amdgcn_rcpf(DENv), acc[i][j]);
                }
        }
    }

    // Epilogue: P = exp2(-acc) -> bf16 Pq[b][q][kb+ty*2..+1]; row partials.
    float ps[2];
#pragma unroll
    for (int i = 0; i < 2; ++i) {
        int q = qb + tx * 2 + i;
        float p0 = __builtin_amdgcn_exp2f(-acc[i][0]);
        float p1 = __builtin_amdgcn_exp2f(-acc[i][1]);
        ps[i] = p0 + p1;
        *(unsigned int*)(Pq + ((size_t)(b * 512 + q) * 512 + kb + ty * 2)) = pk2(p0, p1);
    }
#pragma unroll
    for (int i = 0; i < 2; ++i) {
        ps[i] += __shfl_xor(ps[i], 16, 64);
        ps[i] += __shfl_xor(ps[i], 32, 64);
    }
    if (lane < 16) {
#pragma unroll
        for (int i = 0; i < 2; ++i) redS[w][tx * 2 + i] = ps[i];
    }
    __syncthreads();
    if (tid < 32) {
        float s = ((redS[0][tid] + redS[1][tid]) + (redS[2][tid] + redS[3][tid]))
                + ((redS[4][tid] + redS[5][tid]) + (redS[6][tid] + redS[7][tid]));
        rowpart[(size_t)kt * 2048 + b * 512 + qb + tid] = s;
    }
}

// ---------------------------------------------------------------------------
// Kernel C (R17): out = (P @ V) / rowsum, direct-from-global bf16 fragments.
// P [b][q][k] and V^T [b][n][k] are both row-major in k -> fragments load
// straight from L2 (each 512 KB/batch).  No LDS, no barriers.
// k-order identical to the LDS version -> bit-identical output.
// ---------------------------------------------------------------------------
__global__ __launch_bounds__(512, 2) void av_mfma(
    const char* __restrict__ wsc, float* __restrict__ O)
{
    const unsigned short* Pq = (const unsigned short*)(wsc + OFF_PQ);
    const unsigned short* VT = (const unsigned short*)(wsc + OFF_VT);
    const float* rowpart = (const float*)(wsc + OFF_ROW);

    const int b = blockIdx.z, qb = blockIdx.x * 64, nb = blockIdx.y * 64;
    const int tid = threadIdx.x;
    const int wid = tid >> 6, lane = tid & 63;
    const int ml = lane & 15, quad = lane >> 4;
    const int ms = wid & 3, nh = wid >> 2;     // m-subtile, nt-half

    const unsigned short* Pp  = Pq + (size_t)b * 512 * 512
                              + (size_t)(qb + ms * 16 + ml) * 512 + quad * 8;
    const unsigned short* Vp0 = VT + (size_t)b * 512 * 512
                              + (size_t)(nb + (nh * 2 + 0) * 16 + ml) * 512 + quad * 8;
    const unsigned short* Vp1 = VT + (size_t)b * 512 * 512
                              + (size_t)(nb + (nh * 2 + 1) * 16 + ml) * 512 + quad * 8;

    f32x4v acc0 = {0, 0, 0, 0}, acc1 = {0, 0, 0, 0};
#pragma unroll
    for (int kk = 0; kk < 16; ++kk) {
        bf16x8 af = *(const bf16x8*)(Pp  + kk * 32);
        bf16x8 b0 = *(const bf16x8*)(Vp0 + kk * 32);
        bf16x8 b1 = *(const bf16x8*)(Vp1 + kk * 32);
        acc0 = __builtin_amdgcn_mfma_f32_16x16x32_bf16(af, b0, acc0, 0, 0, 0);
        acc1 = __builtin_amdgcn_mfma_f32_16x16x32_bf16(af, b1, acc1, 0, 0, 0);
    }

    float rr[4];
#pragma unroll
    for (int r = 0; r < 4; ++r) {
        int q = qb + ms * 16 + quad * 4 + r;
        float rs = 0.f;
#pragma unroll
        for (int t8 = 0; t8 < 8; ++t8) rs += rowpart[(size_t)t8 * 2048 + b * 512 + q];
        rr[r] = 1.0f / rs;
    }
#pragma unroll
    for (int r = 0; r < 4; ++r) {
        int q = qb + ms * 16 + quad * 4 + r;
        O[((size_t)b * 512 + q) * 512 + nb + (nh * 2 + 0) * 16 + ml] = acc0[r] * rr[r];
        O[((size_t)b * 512 + q) * 512 + nb + (nh * 2 + 1) * 16 + ml] = acc1[r] * rr[r];
    }
}

extern "C" void kernel_launch(void* const* d_in, const int* in_sizes, int n_in,
                              void* d_out, int out_size, void* d_ws, size_t ws_size,
                              hipStream_t stream) {
    const float* query = (const float*)d_in[0];
    const float* key   = (const float*)d_in[1];
    const float* value = (const float*)d_in[2];
    const float* wq    = (const float*)d_in[3];
    const float* bq    = (const float*)d_in[4];
    const float* wk    = (const float*)d_in[5];
    const float* bk    = (const float*)d_in[6];
    const float* wv    = (const float*)d_in[7];
    // d_in[8] = bv: row-constant -> softmax-invariant, dropped.
    float* out = (float*)d_out;
    char* ws = (char*)d_ws;

    const float c2 = 2.0f * LOG2E;

    preconv<<<dim3(576, 1, 2), 256, 0, stream>>>(query, key, wq, wk, value, ws);
    proj_mfma<<<dim3(32, 4, 2), 512, 0, stream>>>(bq, bk, ws, c2);
    score_kernel<<<dim3(16, 8, Bb), 512, 0, stream>>>(wv, ws);
    av_mfma<<<dim3(8, 8, Bb), 512, 0, stream>>>(ws, out);
}

// Round 4
// 118.356 us; speedup vs baseline: 1.1069x; 1.1069x over previous
//
#include <hip/hip_runtime.h>

#define LOG2E 1.4426950408889634f

// Problem constants
constexpr int Bb = 4, LQ = 512, LK = 512, QS = 512, H = 256, DV = 512;
constexpr int M = 2048;   // B*LQ

// Workspace byte offsets
constexpr size_t OFF_EQT = 0;            // [256][2048] f32 (2 MiB) exp2-domain q proj (pre-scaled 2^-13)
constexpr size_t OFF_EKT = 2u << 20;     // [256][2048] f32 (2 MiB)
constexpr size_t OFF_PQ  = 4u << 20;     // [4][512][512] bf16 (2 MiB) P numerators
constexpr size_t OFF_ROW = 6u << 20;     // [8][2048] f32 rowsum partials
constexpr size_t OFF_VT  = 8u << 20;     // [4][512][512] bf16 V^T ([b][n][k]) (2 MiB)

using bf16x8 = __attribute__((ext_vector_type(8))) short;
using f32x4v = __attribute__((ext_vector_type(4))) float;

__device__ inline unsigned short f2bf(float x) {
    unsigned int u = __float_as_uint(x);
    u += 0x7FFFu + ((u >> 16) & 1u);      // round-to-nearest-even
    return (unsigned short)(u >> 16);
}
// HW packed f32->bf16 (RNE, matches f2bf bit-for-bit on finite inputs).
__device__ inline unsigned int pk2(float lo, float hi) {
    unsigned int r;
    asm("v_cvt_pk_bf16_f32 %0, %1, %2" : "=v"(r) : "v"(lo), "v"(hi));
    return r;
}

// ---------------------------------------------------------------------------
// Kernel A (R18): proj via bf16 MFMA, LDS-staged (R3's direct-global version
// REVERTED — it was L2-latency-bound).  New vs R2: 512 threads (2 waves/SIMD
// instead of 1), 8 waves in (ms,nh) layout: per-wave MFMA halves, per-thread
// staging chain halves.  K-accumulation order per output element identical
// to R2 -> bit-identical EqT/EkT.
//   EqT[n][m] = exp2( clamp( scale*(A[m]·W[n] + bias[n]), ±13 ) - 13 )  (z=0)
//   EkT[n][m] = exp2( clamp( ..., ±13 ) )                                (z=1)
// ---------------------------------------------------------------------------
__global__ __launch_bounds__(512) void proj_mfma(
    const float* __restrict__ query, const float* __restrict__ key,
    const float* __restrict__ wq, const float* __restrict__ wk,
    const float* __restrict__ bq, const float* __restrict__ bk,
    char* __restrict__ ws, float scale)
{
    const int z = blockIdx.z;
    const float* A    = z ? key : query;   // [2048][512]
    const float* W    = z ? wk : wq;       // [256][512]
    const float* bias = z ? bk : bq;
    float* out = (float*)(ws + (z ? OFF_EKT : OFF_EQT));   // [256][2048]
    const float off = z ? 0.0f : 13.0f;

    __shared__ unsigned short Als[64][136];
    __shared__ unsigned short Wls[64][136];
    __shared__ float Ot[64][68];

    const int mb = blockIdx.x * 64, nb = blockIdx.y * 64;
    const int tid = threadIdx.x;
    const int wid = tid >> 6, lane = tid & 63;
    const int ml = lane & 15, quad = lane >> 4;
    const int ms = wid & 3, nh = wid >> 2;    // m-subtile, n-half

    f32x4v acc0 = {0, 0, 0, 0}, acc1 = {0, 0, 0, 0};

    for (int kc = 0; kc < QS; kc += 128) {
        __syncthreads();
#pragma unroll
        for (int it = 0; it < 2; ++it) {
            int u = tid + it * 512;          // 0..1023 units of 8 elems
            int row = u >> 4, c8 = (u & 15) * 8;
            float4 a0 = *(const float4*)(A + (size_t)(mb + row) * 512 + kc + c8);
            float4 a1 = *(const float4*)(A + (size_t)(mb + row) * 512 + kc + c8 + 4);
            uint4 pa = { pk2(a0.x, a0.y), pk2(a0.z, a0.w), pk2(a1.x, a1.y), pk2(a1.z, a1.w) };
            *(uint4*)&Als[row][c8] = pa;
            float4 w0 = *(const float4*)(W + (size_t)(nb + row) * 512 + kc + c8);
            float4 w1 = *(const float4*)(W + (size_t)(nb + row) * 512 + kc + c8 + 4);
            uint4 pw = { pk2(w0.x, w0.y), pk2(w0.z, w0.w), pk2(w1.x, w1.y), pk2(w1.z, w1.w) };
            *(uint4*)&Wls[row][c8] = pw;
        }
        __syncthreads();
#pragma unroll
        for (int s = 0; s < 4; ++s) {
            int k = s * 32 + quad * 8;
            bf16x8 af = *(const bf16x8*)&Als[ms * 16 + ml][k];
            bf16x8 b0 = *(const bf16x8*)&Wls[(nh * 2 + 0) * 16 + ml][k];
            bf16x8 b1 = *(const bf16x8*)&Wls[(nh * 2 + 1) * 16 + ml][k];
            acc0 = __builtin_amdgcn_mfma_f32_16x16x32_bf16(af, b0, acc0, 0, 0, 0);
            acc1 = __builtin_amdgcn_mfma_f32_16x16x32_bf16(af, b1, acc1, 0, 0, 0);
        }
    }

    __syncthreads();
#pragma unroll
    for (int r = 0; r < 4; ++r) {
        Ot[(nh * 2 + 0) * 16 + ml][ms * 16 + quad * 4 + r] = acc0[r];
        Ot[(nh * 2 + 1) * 16 + ml][ms * 16 + quad * 4 + r] = acc1[r];
    }
    __syncthreads();
    {
        int r0 = tid >> 3;            // n-local 0..63
        int c0 = (tid & 7) * 8;       // m-local base
        float bs = bias[nb + r0];
#pragma unroll
        for (int g = 0; g < 2; ++g) {
            float4 v = *(const float4*)&Ot[r0][c0 + g * 4];
            float4 o;
            o.x = __builtin_amdgcn_exp2f(fminf(fmaxf(scale * (v.x + bs), -13.f), 13.f) - off);
            o.y = __builtin_amdgcn_exp2f(fminf(fmaxf(scale * (v.y + bs), -13.f), 13.f) - off);
            o.z = __builtin_amdgcn_exp2f(fminf(fmaxf(scale * (v.z + bs), -13.f), 13.f) - off);
            o.w = __builtin_amdgcn_exp2f(fminf(fmaxf(scale * (v.w + bs), -13.f), 13.f) - off);
            *(float4*)(out + (size_t)(nb + r0) * 2048 + mb + c0 + g * 4) = o;
        }
    }
}

// ---------------------------------------------------------------------------
// Kernel A2: V -> bf16 V^T [b][n][k], once.  (unchanged from R15/R16)
// ---------------------------------------------------------------------------
__global__ __launch_bounds__(256) void vconv(
    const float* __restrict__ V, char* __restrict__ ws)
{
    unsigned short* VT = (unsigned short*)(ws + OFF_VT);
    __shared__ unsigned short T[64][72];
    const int b = blockIdx.z, k0 = blockIdx.x * 64, n0 = blockIdx.y * 64;
    const int tid = threadIdx.x;
    const float* Vb = V + (size_t)b * 512 * 512;
    const int r = tid >> 4, c = (tid & 15) * 4;
#pragma unroll
    for (int it = 0; it < 4; ++it) {
        int kr = r + it * 16;
        float4 v = *(const float4*)(Vb + (size_t)(k0 + kr) * 512 + n0 + c);
        T[c + 0][kr] = f2bf(v.x);
        T[c + 1][kr] = f2bf(v.y);
        T[c + 2][kr] = f2bf(v.z);
        T[c + 3][kr] = f2bf(v.w);
    }
    __syncthreads();
    const int rowO = tid >> 3, colO = (tid & 7) * 8;
#pragma unroll
    for (int it = 0; it < 2; ++it) {
        int n = rowO + it * 32;
        uint4 o = *(const uint4*)&T[n][colO];
        *(uint4*)(VT + ((size_t)b * 512 + n0 + n) * 512 + k0 + colO) = o;
    }
}

// ---------------------------------------------------------------------------
// Kernel B: scores -> P = exp2(-acc) bf16 [b][q][k] + per-ktile row partials.
//   acc(q,k) = sum_h Wv2[h]/(1 + Eq[h][q]*Ek[h][k])   (8-way rcp pairing,
//   s=2^-13 pre-folded into Eq and Wv2 -> exact ratio, no overflow)
// (unchanged from R16/R2)
// ---------------------------------------------------------------------------
__global__ __launch_bounds__(512, 4) void score_kernel(
    const float* __restrict__ wvp, char* __restrict__ ws)
{
    const float* EqT = (const float*)(ws + OFF_EQT);   // [256][2048], pre-scaled 2^-13
    const float* EkT = (const float*)(ws + OFF_EKT);
    unsigned short* Pq = (unsigned short*)(ws + OFF_PQ);  // [4][512][512] bf16
    float* rowpart = (float*)(ws + OFF_ROW);              // [8][2048]

    __shared__ float Qs[64][32];
    __shared__ float Ks[64][64];
    __shared__ float Wv2[H];
    __shared__ float redS[8][32];

    const int b  = blockIdx.z;
    const int qb = blockIdx.x * 32;
    const int kt = blockIdx.y;
    const int kb = kt * 64;
    const int tid = threadIdx.x;
    const int tx = tid & 15;       // q frag: tx*2 + i
    const int ty = tid >> 4;       // k frag: ty*2 + j   (0..31)
    const int w  = tid >> 6;       // 0..7
    const int lane = tid & 63;

    constexpr float S = 0.0001220703125f;   // 2^-13
    if (tid < H) Wv2[tid] = wvp[tid] * (2.0f * LOG2E) * S;   // fold one s into w

    const int mq = b * LQ + qb;
    const int mk = b * LK + kb;

    float acc[2][2] = {};

    for (int h0 = 0; h0 < H; h0 += 64) {
        __syncthreads();   // also covers the Wv2 write on the first pass
        {
            int hq = tid >> 3, cq = (tid & 7) * 4;
            *(float4*)&Qs[hq][cq] = *(const float4*)(EqT + (size_t)(h0 + hq) * M + mq + cq);
            int hk = tid >> 4, ck = (tid & 15) * 4;
            *(float4*)&Ks[hk][ck]      = *(const float4*)(EkT + (size_t)(h0 + hk) * M + mk + ck);
            *(float4*)&Ks[hk + 32][ck] = *(const float4*)(EkT + (size_t)(h0 + hk + 32) * M + mk + ck);
        }
        __syncthreads();
#pragma unroll 2
        for (int hh = 0; hh < 64; hh += 8) {
            float2 qv[8], kv[8];
#pragma unroll
            for (int u = 0; u < 8; ++u) qv[u] = *(const float2*)&Qs[hh + u][tx * 2];
#pragma unroll
            for (int u = 0; u < 8; ++u) kv[u] = *(const float2*)&Ks[hh + u][ty * 2];
            const float4 wA = *(const float4*)&Wv2[h0 + hh];
            const float4 wB = *(const float4*)&Wv2[h0 + hh + 4];
#pragma unroll
            for (int i = 0; i < 2; ++i)
#pragma unroll
                for (int j = 0; j < 2; ++j) {
                    float t[8];
#pragma unroll
                    for (int u = 0; u < 8; ++u)
                        t[u] = fmaf(i ? qv[u].y : qv[u].x, j ? kv[u].y : kv[u].x, S);
                    float t12 = t[0] * t[1], t34 = t[2] * t[3];
                    float n12 = fmaf(wA.x, t[1], wA.y * t[0]);
                    float n34 = fmaf(wA.z, t[3], wA.w * t[2]);
                    float numA = fmaf(n12, t34, n34 * t12);
                    float denA = t12 * t34;
                    float t56 = t[4] * t[5], t78 = t[6] * t[7];
                    float m12 = fmaf(wB.x, t[5], wB.y * t[4]);
                    float m34 = fmaf(wB.z, t[7], wB.w * t[6]);
                    float numB = fmaf(m12, t78, m34 * t56);
                    float denB = t56 * t78;
                    float NUMv = fmaf(numA, denB, numB * denA);
                    float DENv = denA * denB;
                    acc[i][j] = fmaf(NUMv, __builtin_amdgcn_rcpf(DENv), acc[i][j]);
                }
        }
    }

    // Epilogue: P = exp2(-acc) -> bf16 Pq[b][q][kb+ty*2..+1]; row partials.
    float ps[2];
#pragma unroll
    for (int i = 0; i < 2; ++i) {
        int q = qb + tx * 2 + i;
        float p0 = __builtin_amdgcn_exp2f(-acc[i][0]);
        float p1 = __builtin_amdgcn_exp2f(-acc[i][1]);
        ps[i] = p0 + p1;
        *(unsigned int*)(Pq + ((size_t)(b * 512 + q) * 512 + kb + ty * 2)) = pk2(p0, p1);
    }
#pragma unroll
    for (int i = 0; i < 2; ++i) {
        ps[i] += __shfl_xor(ps[i], 16, 64);
        ps[i] += __shfl_xor(ps[i], 32, 64);
    }
    if (lane < 16) {
#pragma unroll
        for (int i = 0; i < 2; ++i) redS[w][tx * 2 + i] = ps[i];
    }
    __syncthreads();
    if (tid < 32) {
        float s = ((redS[0][tid] + redS[1][tid]) + (redS[2][tid] + redS[3][tid]))
                + ((redS[4][tid] + redS[5][tid]) + (redS[6][tid] + redS[7][tid]));
        rowpart[(size_t)kt * 2048 + b * 512 + qb + tid] = s;
    }
}

// ---------------------------------------------------------------------------
// Kernel C: out = (P @ V) / rowsum via bf16 MFMA.  (unchanged from R15/R2:
// LDS-staged from bf16 P and V^T with vector uint4 copies)
// ---------------------------------------------------------------------------
__global__ __launch_bounds__(512, 2) void av_mfma(
    const char* __restrict__ wsc, float* __restrict__ O)
{
    const unsigned short* Pq = (const unsigned short*)(wsc + OFF_PQ);
    const unsigned short* VT = (const unsigned short*)(wsc + OFF_VT);
    const float* rowpart = (const float*)(wsc + OFF_ROW);

    __shared__ unsigned short Pls[64][136];
    __shared__ unsigned short Vls[64][136];

    const int b = blockIdx.z, qb = blockIdx.x * 64, nb = blockIdx.y * 64;
    const int tid = threadIdx.x;
    const int wid = tid >> 6, lane = tid & 63;
    const int ml = lane & 15, quad = lane >> 4;
    const int ms = wid & 3, nh = wid >> 2;     // m-subtile, nt-half
    const unsigned short* Pb = Pq + (size_t)b * 512 * 512;
    const unsigned short* Vb = VT + (size_t)b * 512 * 512;

    f32x4v acc[2] = {{0,0,0,0},{0,0,0,0}};

    for (int kc = 0; kc < LK; kc += 128) {
        __syncthreads();
#pragma unroll
        for (int it = 0; it < 2; ++it) {
            int u = tid + it * 512;
            int row = u >> 4, c8 = (u & 15) * 8;
            *(uint4*)&Pls[row][c8] = *(const uint4*)(Pb + (size_t)(qb + row) * 512 + kc + c8);
            *(uint4*)&Vls[row][c8] = *(const uint4*)(Vb + (size_t)(nb + row) * 512 + kc + c8);
        }
        __syncthreads();
#pragma unroll
        for (int s = 0; s < 4; ++s) {
            int k = s * 32 + quad * 8;
            bf16x8 af = *(const bf16x8*)&Pls[ms * 16 + ml][k];
#pragma unroll
            for (int t = 0; t < 2; ++t) {
                bf16x8 bfr = *(const bf16x8*)&Vls[(nh * 2 + t) * 16 + ml][k];
                acc[t] = __builtin_amdgcn_mfma_f32_16x16x32_bf16(af, bfr, acc[t], 0, 0, 0);
            }
        }
    }

    float rr[4];
#pragma unroll
    for (int r = 0; r < 4; ++r) {
        int q = qb + ms * 16 + quad * 4 + r;
        float rs = 0.f;
#pragma unroll
        for (int t8 = 0; t8 < 8; ++t8) rs += rowpart[(size_t)t8 * 2048 + b * 512 + q];
        rr[r] = 1.0f / rs;
    }
#pragma unroll
    for (int t = 0; t < 2; ++t)
#pragma unroll
        for (int r = 0; r < 4; ++r) {
            int q = qb + ms * 16 + quad * 4 + r;
            O[((size_t)b * 512 + q) * 512 + nb + (nh * 2 + t) * 16 + ml] = acc[t][r] * rr[r];
        }
}

extern "C" void kernel_launch(void* const* d_in, const int* in_sizes, int n_in,
                              void* d_out, int out_size, void* d_ws, size_t ws_size,
                              hipStream_t stream) {
    const float* query = (const float*)d_in[0];
    const float* key   = (const float*)d_in[1];
    const float* value = (const float*)d_in[2];
    const float* wq    = (const float*)d_in[3];
    const float* bq    = (const float*)d_in[4];
    const float* wk    = (const float*)d_in[5];
    const float* bk    = (const float*)d_in[6];
    const float* wv    = (const float*)d_in[7];
    // d_in[8] = bv: row-constant -> softmax-invariant, dropped.
    float* out = (float*)d_out;
    char* ws = (char*)d_ws;

    const float c2 = 2.0f * LOG2E;

    proj_mfma<<<dim3(32, 4, 2), 512, 0, stream>>>(query, key, wq, wk, bq, bk, ws, c2);
    vconv<<<dim3(8, 8, Bb), 256, 0, stream>>>(value, ws);
    score_kernel<<<dim3(16, 8, Bb), 512, 0, stream>>>(wv, ws);
    av_mfma<<<dim3(8, 8, Bb), 512, 0, stream>>>(ws, out);
}